// Round 3
// baseline (394.460 us; speedup 1.0000x reference)
//
#include <hip/hip_runtime.h>

// B=2, S=4096, D=512, H=8, HD=64. INPUTS/OUTPUT ARE FP32 (per reference);
// internal compute bf16 MFMA with fp32 accumulate; ws tensors bf16.
// ws: Q[16][4096][64] | K[16][4096][64] | V^T[16][64][4096] | Y[8192][512]  (bf16)

typedef __bf16 bf16x8 __attribute__((ext_vector_type(8)));
typedef float f32x4 __attribute__((ext_vector_type(4)));
typedef unsigned short u16;

#define MFMA(a, b, c) __builtin_amdgcn_mfma_f32_16x16x32_bf16(a, b, c, 0, 0, 0)

__device__ __forceinline__ u16 f2bf(float f) {
    union { float f; unsigned int i; } v; v.f = f;
    unsigned int i = v.i;
    return (u16)((i + 0x7fffu + ((i >> 16) & 1u)) >> 16);
}
__device__ __forceinline__ ushort4 f4_to_bf4(float4 v) {
    ushort4 r;
    r.x = f2bf(v.x); r.y = f2bf(v.y); r.z = f2bf(v.z); r.w = f2bf(v.w);
    return r;
}
// async global->LDS, 16B/lane (m97 contiguous pattern; bf16 sources only)
__device__ __forceinline__ void load_lds16(const u16* g, u16* l) {
    __builtin_amdgcn_global_load_lds(
        (const __attribute__((address_space(1))) void*)g,
        (__attribute__((address_space(3))) void*)l, 16, 0, 0);
}

// ---------------------------------------------------------------------------
// GEMM1: qkv = x @ Wqkv^T + bqkv -> Q[bh][s][64], K[bh][s][64], V^T[bh][64][s]
// fp32 in, bf16 ws out. 128x128 tile, BK=32, 4 waves, 4x4 16x16x32 MFMAs.
// Staging: fp32 global -> cvt bf16 in regs -> ds_write.
// ---------------------------------------------------------------------------
__global__ __launch_bounds__(256) void gemm_qkv_k(
    const float* __restrict__ X, const float* __restrict__ W,
    const float* __restrict__ bias,
    u16* __restrict__ Qo, u16* __restrict__ Ko, u16* __restrict__ Vto)
{
    __shared__ u16 As[128 * 32];
    __shared__ u16 Bs[128 * 32];
    const int K = 512;
    const int tid = threadIdx.x, wave = tid >> 6, lane = tid & 63;
    const int l15 = lane & 15, quad = lane >> 4;
    const int bm = blockIdx.x * 128, bn = blockIdx.y * 128;
    const int wr = wave >> 1, wc = wave & 1;
    const int srow = tid >> 1;          // 0..127 staging row
    const int sc0 = (tid & 1) * 16;     // col offset 0/16

    f32x4 acc[4][4] = {};

    for (int k0 = 0; k0 < K; k0 += 32) {
        __syncthreads();
#pragma unroll
        for (int j = 0; j < 4; j++) {
            float4 xv = *(const float4*)&X[(bm + srow) * K + k0 + sc0 + j * 4];
            float4 wv = *(const float4*)&W[(bn + srow) * K + k0 + sc0 + j * 4];
            *(ushort4*)&As[srow * 32 + sc0 + j * 4] = f4_to_bf4(xv);
            *(ushort4*)&Bs[srow * 32 + sc0 + j * 4] = f4_to_bf4(wv);
        }
        __syncthreads();
        bf16x8 a[4], b[4];
#pragma unroll
        for (int i = 0; i < 4; i++)
            a[i] = *(const bf16x8*)&As[(wr * 64 + i * 16 + l15) * 32 + quad * 8];
#pragma unroll
        for (int j = 0; j < 4; j++)
            b[j] = *(const bf16x8*)&Bs[(wc * 64 + j * 16 + l15) * 32 + quad * 8];
#pragma unroll
        for (int i = 0; i < 4; i++)
#pragma unroll
            for (int j = 0; j < 4; j++)
                acc[i][j] = MFMA(a[i], b[j], acc[i][j]);
    }

    // C/D layout: row = quad*4 + reg, col = l15 (m89-verified).
    const int nbase = bn + wc * 64;
    const int which = nbase >> 9;  // 0=q 1=k 2=v (64-col slab never straddles)
#pragma unroll
    for (int j = 0; j < 4; j++) {
        const int n_g = nbase + j * 16 + l15;
        const float bv = bias[n_g];
        const int d = n_g & 511, h = d >> 6, hd = d & 63;
#pragma unroll
        for (int i = 0; i < 4; i++) {
            const int m0 = bm + wr * 64 + i * 16 + quad * 4;
            const int b_ = m0 >> 12, s0 = m0 & 4095;
            const int bhh = b_ * 8 + h;
            if (which == 2) {
                ushort4 pk;
                pk.x = f2bf(acc[i][j][0] + bv);
                pk.y = f2bf(acc[i][j][1] + bv);
                pk.z = f2bf(acc[i][j][2] + bv);
                pk.w = f2bf(acc[i][j][3] + bv);
                *(ushort4*)&Vto[(bhh * 64 + hd) * 4096 + s0] = pk;
            } else {
                u16* dst = (which == 0) ? Qo : Ko;
#pragma unroll
                for (int r = 0; r < 4; r++)
                    dst[(bhh * 4096 + s0 + r) * 64 + hd] = f2bf(acc[i][j][r] + bv);
            }
        }
    }
}

// ---------------------------------------------------------------------------
// Flash attention, causal. Block = 128 q rows of one (b,h); 4 waves x 32 rows.
// All operands bf16 ws. Plain padded staging (stride 80 u16), no swizzles.
// ---------------------------------------------------------------------------
#define LS 80  // LDS row stride in u16

__global__ __launch_bounds__(256) void attn_k(
    const u16* __restrict__ Q, const u16* __restrict__ Kk,
    const u16* __restrict__ Vt, u16* __restrict__ Y)
{
    __shared__ u16 Ks[64 * LS];        // [key][hd]
    __shared__ u16 Vs[64 * LS];        // [hd][key]
    __shared__ u16 Ps[4 * 32 * LS];    // per-wave P, [q][key]

    const int tid = threadIdx.x, wave = tid >> 6, lane = tid & 63;
    const int l15 = lane & 15, quad = lane >> 4;
    const int bh = blockIdx.y;
    const int q0 = blockIdx.x * 128;
    const int base_r = q0 + wave * 32;

    // Q fragments (A-layout: m=l15, k=quad*8+j).
    bf16x8 qf[2][2];
#pragma unroll
    for (int t = 0; t < 2; t++)
#pragma unroll
        for (int ks = 0; ks < 2; ks++)
            qf[t][ks] = *(const bf16x8*)&Q[(bh * 4096 + base_r + t * 16 + l15) * 64 + ks * 32 + quad * 8];

    f32x4 o[2][4] = {};
    float m_st[2][4], l_st[2][4];
#pragma unroll
    for (int t = 0; t < 2; t++)
#pragma unroll
        for (int r = 0; r < 4; r++) { m_st[t][r] = -1e30f; l_st[t][r] = 0.0f; }

    const int srow = tid >> 3;             // 0..31
    const int scol = (tid & 7) * 8;        // 0..56

    const int ntiles = (q0 >> 6) + 2;
    for (int kt = 0; kt < ntiles; kt++) {
        const int k0 = kt * 64;
        __syncthreads();
#pragma unroll
        for (int half = 0; half < 2; half++) {
            const int row = half * 32 + srow;
            bf16x8 kv = *(const bf16x8*)&Kk[(bh * 4096 + k0 + row) * 64 + scol];
            bf16x8 vv = *(const bf16x8*)&Vt[(bh * 64 + row) * 4096 + k0 + scol];
            *(bf16x8*)&Ks[row * LS + scol] = kv;
            *(bf16x8*)&Vs[row * LS + scol] = vv;
        }
        __syncthreads();

        if (k0 <= base_r) {  // causal: this wave's rows need this KV tile
            // ---- S = Q K^T ----
            f32x4 sc[2][4];
#pragma unroll
            for (int j = 0; j < 4; j++) {
                const int krow = j * 16 + l15;
                bf16x8 kf0 = *(const bf16x8*)&Ks[krow * LS + quad * 8];
                bf16x8 kf1 = *(const bf16x8*)&Ks[krow * LS + 32 + quad * 8];
#pragma unroll
                for (int t = 0; t < 2; t++) {
                    f32x4 s = {};
                    s = MFMA(qf[t][0], kf0, s);
                    s = MFMA(qf[t][1], kf1, s);
                    sc[t][j] = s;
                }
            }
            // ---- online softmax per row-tile t ----
#pragma unroll
            for (int t = 0; t < 2; t++) {
                const bool needmask = (k0 + 63) > (base_r + t * 16);
                float sv[4][4];
#pragma unroll
                for (int j = 0; j < 4; j++)
#pragma unroll
                    for (int r = 0; r < 4; r++) {
                        float v = sc[t][j][r] * 0.125f;  // 1/sqrt(64)
                        if (needmask) {
                            const int key = k0 + j * 16 + l15;
                            const int row = base_r + t * 16 + quad * 4 + r;
                            if (key > row) v = -1e30f;
                        }
                        sv[j][r] = v;
                    }
                float rmax[4], mnew[4], alpha[4], rsum[4];
#pragma unroll
                for (int r = 0; r < 4; r++)
                    rmax[r] = fmaxf(fmaxf(sv[0][r], sv[1][r]), fmaxf(sv[2][r], sv[3][r]));
#pragma unroll
                for (int off = 1; off < 16; off <<= 1)
#pragma unroll
                    for (int r = 0; r < 4; r++)
                        rmax[r] = fmaxf(rmax[r], __shfl_xor(rmax[r], off, 16));
#pragma unroll
                for (int r = 0; r < 4; r++) {
                    mnew[r] = fmaxf(m_st[t][r], rmax[r]);
                    alpha[r] = __expf(m_st[t][r] - mnew[r]);
                    m_st[t][r] = mnew[r];
                    rsum[r] = 0.0f;
                }
#pragma unroll
                for (int j = 0; j < 4; j++)
#pragma unroll
                    for (int r = 0; r < 4; r++) {
                        float p = __expf(sv[j][r] - mnew[r]);
                        sv[j][r] = p;
                        rsum[r] += p;
                    }
#pragma unroll
                for (int off = 1; off < 16; off <<= 1)
#pragma unroll
                    for (int r = 0; r < 4; r++)
                        rsum[r] += __shfl_xor(rsum[r], off, 16);
#pragma unroll
                for (int r = 0; r < 4; r++)
                    l_st[t][r] = l_st[t][r] * alpha[r] + rsum[r];
#pragma unroll
                for (int n = 0; n < 4; n++)
#pragma unroll
                    for (int r = 0; r < 4; r++)
                        o[t][n][r] *= alpha[r];
                // P (C-layout) -> LDS bf16, plain row-major (padded)
                u16* P = &Ps[wave * 32 * LS];
#pragma unroll
                for (int j = 0; j < 4; j++)
#pragma unroll
                    for (int r = 0; r < 4; r++) {
                        const int row = t * 16 + quad * 4 + r;
                        const int col = j * 16 + l15;
                        P[row * LS + col] = f2bf(sv[j][r]);
                    }
            }
            // ---- O += P V ----
            bf16x8 pf[2][2];
#pragma unroll
            for (int t = 0; t < 2; t++)
#pragma unroll
                for (int ks = 0; ks < 2; ks++)
                    pf[t][ks] = *(const bf16x8*)&Ps[wave * 32 * LS + (t * 16 + l15) * LS +
                                                   ks * 32 + quad * 8];
#pragma unroll
            for (int n = 0; n < 4; n++) {
                const int vrow = n * 16 + l15;
                bf16x8 vf0 = *(const bf16x8*)&Vs[vrow * LS + quad * 8];
                bf16x8 vf1 = *(const bf16x8*)&Vs[vrow * LS + 32 + quad * 8];
#pragma unroll
                for (int t = 0; t < 2; t++) {
                    o[t][n] = MFMA(pf[t][0], vf0, o[t][n]);
                    o[t][n] = MFMA(pf[t][1], vf1, o[t][n]);
                }
            }
        }
    }

    // epilogue: y[b][s][h*64+hd] = o / l  (bf16 ws)
    const int b_ = bh >> 3, h = bh & 7;
#pragma unroll
    for (int t = 0; t < 2; t++)
#pragma unroll
        for (int r = 0; r < 4; r++) {
            const float inv = 1.0f / l_st[t][r];
            const int s = base_r + t * 16 + quad * 4 + r;
            const int base = (b_ * 4096 + s) * 512 + h * 64;
#pragma unroll
            for (int n = 0; n < 4; n++)
                Y[base + n * 16 + l15] = f2bf(o[t][n][r] * inv);
        }
}

// ---------------------------------------------------------------------------
// GEMM3: out = y @ Wo^T + bo  (M=8192, N=512, K=512). A bf16 ws, B/bias/out fp32.
// ---------------------------------------------------------------------------
__global__ __launch_bounds__(256) void gemm_o_k(
    const u16* __restrict__ X, const float* __restrict__ W,
    const float* __restrict__ bias, float* __restrict__ Out)
{
    __shared__ u16 As[128 * 32];
    __shared__ u16 Bs[128 * 32];
    const int K = 512;
    const int tid = threadIdx.x, wave = tid >> 6, lane = tid & 63;
    const int l15 = lane & 15, quad = lane >> 4;
    const int bm = blockIdx.x * 128, bn = blockIdx.y * 128;
    const int wr = wave >> 1, wc = wave & 1;
    const int arow = lane >> 2;
    const int acol = (lane & 3) * 8;
    const int srow = tid >> 1;
    const int sc0 = (tid & 1) * 16;

    f32x4 acc[4][4] = {};

    for (int k0 = 0; k0 < K; k0 += 32) {
        __syncthreads();
#pragma unroll
        for (int ii = 0; ii < 2; ii++) {
            const int inst = wave * 2 + ii;
            const int row = inst * 16 + arow;
            load_lds16(&X[(bm + row) * K + k0 + acol], &As[inst * 512]);
        }
#pragma unroll
        for (int j = 0; j < 4; j++) {
            float4 wv = *(const float4*)&W[(bn + srow) * K + k0 + sc0 + j * 4];
            *(ushort4*)&Bs[srow * 32 + sc0 + j * 4] = f4_to_bf4(wv);
        }
        __syncthreads();
        bf16x8 a[4], b[4];
#pragma unroll
        for (int i = 0; i < 4; i++)
            a[i] = *(const bf16x8*)&As[(wr * 64 + i * 16 + l15) * 32 + quad * 8];
#pragma unroll
        for (int j = 0; j < 4; j++)
            b[j] = *(const bf16x8*)&Bs[(wc * 64 + j * 16 + l15) * 32 + quad * 8];
#pragma unroll
        for (int i = 0; i < 4; i++)
#pragma unroll
            for (int j = 0; j < 4; j++)
                acc[i][j] = MFMA(a[i], b[j], acc[i][j]);
    }

#pragma unroll
    for (int j = 0; j < 4; j++) {
        const int n_g = bn + wc * 64 + j * 16 + l15;
        const float bv = bias[n_g];
#pragma unroll
        for (int i = 0; i < 4; i++) {
            const int m0 = bm + wr * 64 + i * 16 + quad * 4;
#pragma unroll
            for (int r = 0; r < 4; r++)
                Out[(m0 + r) * 512 + n_g] = acc[i][j][r] + bv;
        }
    }
}

extern "C" void kernel_launch(void* const* d_in, const int* in_sizes, int n_in,
                              void* d_out, int out_size, void* d_ws, size_t ws_size,
                              hipStream_t stream) {
    (void)in_sizes; (void)n_in; (void)out_size; (void)ws_size;
    const float* x    = (const float*)d_in[0];   // [2,4096,512] fp32
    const float* Wqkv = (const float*)d_in[1];   // [1536,512]  fp32
    const float* bqkv = (const float*)d_in[2];   // [1536]      fp32
    const float* Wo   = (const float*)d_in[3];   // [512,512]   fp32
    const float* bo   = (const float*)d_in[4];   // [512]       fp32
    float* out = (float*)d_out;                  // [2,4096,512] fp32

    u16* q_ws  = (u16*)d_ws;                 // [16][4096][64] bf16
    u16* k_ws  = q_ws + 4194304;             // [16][4096][64] bf16
    u16* vt_ws = k_ws + 4194304;             // [16][64][4096] bf16
    u16* y_ws  = vt_ws + 4194304;            // [8192][512]    bf16

    gemm_qkv_k<<<dim3(64, 12), 256, 0, stream>>>(x, Wqkv, bqkv, q_ws, k_ws, vt_ws);
    attn_k<<<dim3(32, 16), 256, 0, stream>>>(q_ws, k_ws, vt_ws, y_ws);
    gemm_o_k<<<dim3(64, 4), 256, 0, stream>>>(y_ws, Wo, bo, out);
}

// Round 5
// 272.409 us; speedup vs baseline: 1.4480x; 1.4480x over previous
//
#include <hip/hip_runtime.h>

// B=2, S=4096, D=512, H=8, HD=64. fp32 in/out; bf16 MFMA internally.
// ws: Q[16][4096][64] | K[16][4096][64] | V^T[16][64][4096] | Y[8192][512] (bf16)
//     | xb[2*4096*512] | wqkvb[1536*512] | wob[512*512] (bf16, if ws allows)

typedef __bf16 bf16x8 __attribute__((ext_vector_type(8)));
typedef float f32x4 __attribute__((ext_vector_type(4)));
typedef unsigned short u16;

#define MFMA(a, b, c) __builtin_amdgcn_mfma_f32_16x16x32_bf16(a, b, c, 0, 0, 0)

// softmax runs in exp2 domain: Q pre-scaled by 1/sqrt(64) * log2(e)
#define QSCALE 0.18033688011112042f

// v_exp_f32: D = 2^S0  (HIP has no __exp2f device intrinsic; use the builtin)
__device__ __forceinline__ float exp2_fast(float x) {
    return __builtin_amdgcn_exp2f(x);
}

__device__ __forceinline__ u16 f2bf(float f) {
    union { float f; unsigned int i; } v; v.f = f;
    unsigned int i = v.i;
    return (u16)((i + 0x7fffu + ((i >> 16) & 1u)) >> 16);
}
__device__ __forceinline__ ushort4 f4_to_bf4(float4 v) {
    ushort4 r;
    r.x = f2bf(v.x); r.y = f2bf(v.y); r.z = f2bf(v.z); r.w = f2bf(v.w);
    return r;
}
__device__ __forceinline__ void load_lds16(const u16* g, u16* l) {
    __builtin_amdgcn_global_load_lds(
        (const __attribute__((address_space(1))) void*)g,
        (__attribute__((address_space(3))) void*)l, 16, 0, 0);
}

// ---------------------------------------------------------------------------
// fp32 -> bf16 bulk convert (memory-bound)
// ---------------------------------------------------------------------------
__global__ __launch_bounds__(256) void cvt_k(const float* __restrict__ in,
                                             u16* __restrict__ out, int n4) {
    int i = blockIdx.x * 256 + threadIdx.x;
    if (i < n4) {
        float4 v = ((const float4*)in)[i];
        ((ushort4*)out)[i] = f4_to_bf4(v);
    }
}

// ---------------------------------------------------------------------------
// GEMM1 (bf16 inputs): qkv = x @ Wqkv^T + b -> Q(scaled)/K [bh][s][64], V^T [bh][64][s]
// ---------------------------------------------------------------------------
__global__ __launch_bounds__(256) void gemm_qkv_bf(
    const u16* __restrict__ X, const u16* __restrict__ W,
    const float* __restrict__ bias,
    u16* __restrict__ Qo, u16* __restrict__ Ko, u16* __restrict__ Vto)
{
    __shared__ u16 As[128 * 32];
    __shared__ u16 Bs[128 * 32];
    const int K = 512;
    const int tid = threadIdx.x, wave = tid >> 6, lane = tid & 63;
    const int l15 = lane & 15, quad = lane >> 4;
    const int bm = blockIdx.x * 128, bn = blockIdx.y * 128;
    const int wr = wave >> 1, wc = wave & 1;
    const int arow = lane >> 2;
    const int acol = (lane & 3) * 8;

    f32x4 acc[4][4] = {};
    for (int k0 = 0; k0 < K; k0 += 32) {
        __syncthreads();
#pragma unroll
        for (int ii = 0; ii < 2; ii++) {
            const int inst = wave * 2 + ii;
            const int row = inst * 16 + arow;
            load_lds16(&X[(bm + row) * K + k0 + acol], &As[inst * 512]);
            load_lds16(&W[(bn + row) * K + k0 + acol], &Bs[inst * 512]);
        }
        __syncthreads();
        bf16x8 a[4], b[4];
#pragma unroll
        for (int i = 0; i < 4; i++)
            a[i] = *(const bf16x8*)&As[(wr * 64 + i * 16 + l15) * 32 + quad * 8];
#pragma unroll
        for (int j = 0; j < 4; j++)
            b[j] = *(const bf16x8*)&Bs[(wc * 64 + j * 16 + l15) * 32 + quad * 8];
#pragma unroll
        for (int i = 0; i < 4; i++)
#pragma unroll
            for (int j = 0; j < 4; j++)
                acc[i][j] = MFMA(a[i], b[j], acc[i][j]);
    }

    const int nbase = bn + wc * 64;
    const int which = nbase >> 9;  // 0=q 1=k 2=v
    const float osc = (which == 0) ? QSCALE : 1.0f;
#pragma unroll
    for (int j = 0; j < 4; j++) {
        const int n_g = nbase + j * 16 + l15;
        const float bv = bias[n_g];
        const int d = n_g & 511, h = d >> 6, hd = d & 63;
#pragma unroll
        for (int i = 0; i < 4; i++) {
            const int m0 = bm + wr * 64 + i * 16 + quad * 4;
            const int b_ = m0 >> 12, s0 = m0 & 4095;
            const int bhh = b_ * 8 + h;
            if (which == 2) {
                ushort4 pk;
                pk.x = f2bf(acc[i][j][0] + bv);
                pk.y = f2bf(acc[i][j][1] + bv);
                pk.z = f2bf(acc[i][j][2] + bv);
                pk.w = f2bf(acc[i][j][3] + bv);
                *(ushort4*)&Vto[(bhh * 64 + hd) * 4096 + s0] = pk;
            } else {
                u16* dst = (which == 0) ? Qo : Ko;
#pragma unroll
                for (int r = 0; r < 4; r++)
                    dst[(bhh * 4096 + s0 + r) * 64 + hd] = f2bf((acc[i][j][r] + bv) * osc);
            }
        }
    }
}

// fallback: fp32 inputs, convert while staging (round-3 proven path + Q scale)
__global__ __launch_bounds__(256) void gemm_qkv_f32(
    const float* __restrict__ X, const float* __restrict__ W,
    const float* __restrict__ bias,
    u16* __restrict__ Qo, u16* __restrict__ Ko, u16* __restrict__ Vto)
{
    __shared__ u16 As[128 * 32];
    __shared__ u16 Bs[128 * 32];
    const int K = 512;
    const int tid = threadIdx.x, wave = tid >> 6, lane = tid & 63;
    const int l15 = lane & 15, quad = lane >> 4;
    const int bm = blockIdx.x * 128, bn = blockIdx.y * 128;
    const int wr = wave >> 1, wc = wave & 1;
    const int srow = tid >> 1;
    const int sc0 = (tid & 1) * 16;

    f32x4 acc[4][4] = {};
    for (int k0 = 0; k0 < K; k0 += 32) {
        __syncthreads();
#pragma unroll
        for (int j = 0; j < 4; j++) {
            float4 xv = *(const float4*)&X[(bm + srow) * K + k0 + sc0 + j * 4];
            float4 wv = *(const float4*)&W[(bn + srow) * K + k0 + sc0 + j * 4];
            *(ushort4*)&As[srow * 32 + sc0 + j * 4] = f4_to_bf4(xv);
            *(ushort4*)&Bs[srow * 32 + sc0 + j * 4] = f4_to_bf4(wv);
        }
        __syncthreads();
        bf16x8 a[4], b[4];
#pragma unroll
        for (int i = 0; i < 4; i++)
            a[i] = *(const bf16x8*)&As[(wr * 64 + i * 16 + l15) * 32 + quad * 8];
#pragma unroll
        for (int j = 0; j < 4; j++)
            b[j] = *(const bf16x8*)&Bs[(wc * 64 + j * 16 + l15) * 32 + quad * 8];
#pragma unroll
        for (int i = 0; i < 4; i++)
#pragma unroll
            for (int j = 0; j < 4; j++)
                acc[i][j] = MFMA(a[i], b[j], acc[i][j]);
    }
    const int nbase = bn + wc * 64;
    const int which = nbase >> 9;
    const float osc = (which == 0) ? QSCALE : 1.0f;
#pragma unroll
    for (int j = 0; j < 4; j++) {
        const int n_g = nbase + j * 16 + l15;
        const float bv = bias[n_g];
        const int d = n_g & 511, h = d >> 6, hd = d & 63;
#pragma unroll
        for (int i = 0; i < 4; i++) {
            const int m0 = bm + wr * 64 + i * 16 + quad * 4;
            const int b_ = m0 >> 12, s0 = m0 & 4095;
            const int bhh = b_ * 8 + h;
            if (which == 2) {
                ushort4 pk;
                pk.x = f2bf(acc[i][j][0] + bv);
                pk.y = f2bf(acc[i][j][1] + bv);
                pk.z = f2bf(acc[i][j][2] + bv);
                pk.w = f2bf(acc[i][j][3] + bv);
                *(ushort4*)&Vto[(bhh * 64 + hd) * 4096 + s0] = pk;
            } else {
                u16* dst = (which == 0) ? Qo : Ko;
#pragma unroll
                for (int r = 0; r < 4; r++)
                    dst[(bhh * 4096 + s0 + r) * 64 + hd] = f2bf((acc[i][j][r] + bv) * osc);
            }
        }
    }
}

// ---------------------------------------------------------------------------
// Flash attention, causal, S^T orientation. 64 q-rows/block, 4 waves x 16 rows.
// Grid x reversed (heavy blocks first). Register prefetch of next K/V tile.
// LS=72 (144B row stride == 4 banks/row -> 2-way max = free).
// ---------------------------------------------------------------------------
#define LS 72

__global__ __launch_bounds__(256, 4) void attn_k(
    const u16* __restrict__ Q, const u16* __restrict__ Kk,
    const u16* __restrict__ Vt, u16* __restrict__ Y)
{
    __shared__ u16 Ks[64 * LS];        // [key][hd]
    __shared__ u16 Vs[64 * LS];        // [hd][key]
    __shared__ u16 Ps[4 * 16 * LS];    // per-wave P, [qrow][key]

    const int tid = threadIdx.x, wave = tid >> 6, lane = tid & 63;
    const int l15 = lane & 15, quad = lane >> 4;
    const int bh = blockIdx.y;
    const int qt = (int)(gridDim.x - 1) - (int)blockIdx.x;  // heavy first
    const int q0 = qt * 64;
    const int base_r = q0 + wave * 16;

    // Q fragments (B-operand of S^T = K Q^T): n=qrow=l15, k=hd
    const u16* qptr = &Q[(bh * 4096 + base_r + l15) * 64];
    bf16x8 qf0 = *(const bf16x8*)&qptr[quad * 8];
    bf16x8 qf1 = *(const bf16x8*)&qptr[32 + quad * 8];

    f32x4 o[4] = {};
    float m_st = -1e30f, l_st = 0.0f;

    // staging: thread -> K/V row tid>>2, 32B chunk (tid&3)
    const int srow = tid >> 2;
    const int scol = (tid & 3) * 16;
    const u16* Kg = &Kk[(bh * 4096 + srow) * 64 + scol];
    const u16* Vg = &Vt[(bh * 64 + srow) * 4096 + scol];

    const int ntiles = qt + 1;
    bf16x8 pk0 = *(const bf16x8*)&Kg[0];
    bf16x8 pk1 = *(const bf16x8*)&Kg[8];
    bf16x8 pv0 = *(const bf16x8*)&Vg[0];
    bf16x8 pv1 = *(const bf16x8*)&Vg[8];

    for (int kt = 0; kt < ntiles; kt++) {
        const int k0 = kt * 64;
        __syncthreads();
        *(bf16x8*)&Ks[srow * LS + scol] = pk0;
        *(bf16x8*)&Ks[srow * LS + scol + 8] = pk1;
        *(bf16x8*)&Vs[srow * LS + scol] = pv0;
        *(bf16x8*)&Vs[srow * LS + scol + 8] = pv1;
        if (kt + 1 < ntiles) {
            pk0 = *(const bf16x8*)&Kg[(k0 + 64) * 64];
            pk1 = *(const bf16x8*)&Kg[(k0 + 64) * 64 + 8];
            pv0 = *(const bf16x8*)&Vg[k0 + 64];
            pv1 = *(const bf16x8*)&Vg[k0 + 64 + 8];
        }
        __syncthreads();

        // ---- S^T = K Q^T : sc[j] row=key j*16+quad*4+r, col=qrow=l15 ----
        f32x4 sc[4];
#pragma unroll
        for (int j = 0; j < 4; j++) {
            const int krow = j * 16 + l15;
            bf16x8 kf0 = *(const bf16x8*)&Ks[krow * LS + quad * 8];
            bf16x8 kf1 = *(const bf16x8*)&Ks[krow * LS + 32 + quad * 8];
            f32x4 s = {};
            s = MFMA(kf0, qf0, s);
            s = MFMA(kf1, qf1, s);
            sc[j] = s;
        }
        // ---- online softmax (exp2 domain; each lane owns qrow=l15) ----
        const bool needmask = (k0 + 63 > base_r);
        float sv[4][4];
#pragma unroll
        for (int j = 0; j < 4; j++)
#pragma unroll
            for (int r = 0; r < 4; r++) {
                float v = sc[j][r];
                if (needmask) {
                    const int key = k0 + j * 16 + quad * 4 + r;
                    if (key > base_r + l15) v = -1e30f;
                }
                sv[j][r] = v;
            }
        float rmax = sv[0][0];
#pragma unroll
        for (int j = 0; j < 4; j++)
#pragma unroll
            for (int r = 0; r < 4; r++) rmax = fmaxf(rmax, sv[j][r]);
        rmax = fmaxf(rmax, __shfl_xor(rmax, 16));
        rmax = fmaxf(rmax, __shfl_xor(rmax, 32));
        const float mnew = fmaxf(m_st, rmax);
        const float alpha = exp2_fast(m_st - mnew);
        m_st = mnew;
        float rsum = 0.0f;
#pragma unroll
        for (int j = 0; j < 4; j++)
#pragma unroll
            for (int r = 0; r < 4; r++) {
                float p = exp2_fast(sv[j][r] - mnew);
                sv[j][r] = p;
                rsum += p;
            }
        rsum += __shfl_xor(rsum, 16);
        rsum += __shfl_xor(rsum, 32);
        l_st = l_st * alpha + rsum;
        float alr[4];
#pragma unroll
        for (int r = 0; r < 4; r++) alr[r] = __shfl(alpha, quad * 4 + r, 16);
#pragma unroll
        for (int n = 0; n < 4; n++)
#pragma unroll
            for (int r = 0; r < 4; r++) o[n][r] *= alr[r];
        // ---- P -> LDS (row-contiguous 8B packs), read back as A-frag ----
        u16* P = &Ps[wave * 16 * LS];
#pragma unroll
        for (int j = 0; j < 4; j++) {
            ushort4 w;
            w.x = f2bf(sv[j][0]); w.y = f2bf(sv[j][1]);
            w.z = f2bf(sv[j][2]); w.w = f2bf(sv[j][3]);
            *(ushort4*)&P[l15 * LS + j * 16 + quad * 4] = w;
        }
        bf16x8 pf0 = *(const bf16x8*)&P[l15 * LS + quad * 8];
        bf16x8 pf1 = *(const bf16x8*)&P[l15 * LS + 32 + quad * 8];
        // ---- O += P V : B = V^T rows ----
#pragma unroll
        for (int n = 0; n < 4; n++) {
            const int vrow = n * 16 + l15;
            bf16x8 vf0 = *(const bf16x8*)&Vs[vrow * LS + quad * 8];
            bf16x8 vf1 = *(const bf16x8*)&Vs[vrow * LS + 32 + quad * 8];
            o[n] = MFMA(pf0, vf0, o[n]);
            o[n] = MFMA(pf1, vf1, o[n]);
        }
    }

    // epilogue: o row=qrow(quad*4+r), col=hd(n*16+l15); l_st lives at lane l15=qrow
    const float inv = 1.0f / l_st;
    float ivr[4];
#pragma unroll
    for (int r = 0; r < 4; r++) ivr[r] = __shfl(inv, quad * 4 + r, 16);
    const int b_ = bh >> 3, h = bh & 7;
#pragma unroll
    for (int r = 0; r < 4; r++) {
        const int s = base_r + quad * 4 + r;
        const int base = (b_ * 4096 + s) * 512 + h * 64;
#pragma unroll
        for (int n = 0; n < 4; n++)
            Y[base + n * 16 + l15] = f2bf(o[n][r] * ivr[r]);
    }
}

// ---------------------------------------------------------------------------
// GEMM3: out = y @ Wo^T + bo. A bf16 ws; W bf16 (pre-cvt) or fp32 fallback.
// ---------------------------------------------------------------------------
template <typename WT>
__global__ __launch_bounds__(256) void gemm_o_k(
    const u16* __restrict__ X, const WT* __restrict__ W,
    const float* __restrict__ bias, float* __restrict__ Out)
{
    __shared__ u16 As[128 * 32];
    __shared__ u16 Bs[128 * 32];
    const int K = 512;
    const int tid = threadIdx.x, wave = tid >> 6, lane = tid & 63;
    const int l15 = lane & 15, quad = lane >> 4;
    const int bm = blockIdx.x * 128, bn = blockIdx.y * 128;
    const int wr = wave >> 1, wc = wave & 1;
    const int arow = lane >> 2;
    const int acol = (lane & 3) * 8;
    const int srow = tid >> 1;
    const int sc0 = (tid & 1) * 16;

    f32x4 acc[4][4] = {};
    for (int k0 = 0; k0 < K; k0 += 32) {
        __syncthreads();
#pragma unroll
        for (int ii = 0; ii < 2; ii++) {
            const int inst = wave * 2 + ii;
            const int row = inst * 16 + arow;
            load_lds16(&X[(bm + row) * K + k0 + acol], &As[inst * 512]);
        }
        if constexpr (sizeof(WT) == 2) {
#pragma unroll
            for (int ii = 0; ii < 2; ii++) {
                const int inst = wave * 2 + ii;
                const int row = inst * 16 + arow;
                load_lds16((const u16*)&W[(bn + row) * K + k0 + acol], &Bs[inst * 512]);
            }
        } else {
#pragma unroll
            for (int j = 0; j < 4; j++) {
                float4 wv = *(const float4*)&W[(bn + srow) * K + k0 + sc0 + j * 4];
                *(ushort4*)&Bs[srow * 32 + sc0 + j * 4] = f4_to_bf4(wv);
            }
        }
        __syncthreads();
        bf16x8 a[4], b[4];
#pragma unroll
        for (int i = 0; i < 4; i++)
            a[i] = *(const bf16x8*)&As[(wr * 64 + i * 16 + l15) * 32 + quad * 8];
#pragma unroll
        for (int j = 0; j < 4; j++)
            b[j] = *(const bf16x8*)&Bs[(wc * 64 + j * 16 + l15) * 32 + quad * 8];
#pragma unroll
        for (int i = 0; i < 4; i++)
#pragma unroll
            for (int j = 0; j < 4; j++)
                acc[i][j] = MFMA(a[i], b[j], acc[i][j]);
    }
#pragma unroll
    for (int j = 0; j < 4; j++) {
        const int n_g = bn + wc * 64 + j * 16 + l15;
        const float bv = bias[n_g];
#pragma unroll
        for (int i = 0; i < 4; i++) {
            const int m0 = bm + wr * 64 + i * 16 + quad * 4;
#pragma unroll
            for (int r = 0; r < 4; r++)
                Out[(m0 + r) * 512 + n_g] = acc[i][j][r] + bv;
        }
    }
}

extern "C" void kernel_launch(void* const* d_in, const int* in_sizes, int n_in,
                              void* d_out, int out_size, void* d_ws, size_t ws_size,
                              hipStream_t stream) {
    (void)in_sizes; (void)n_in; (void)out_size;
    const float* x    = (const float*)d_in[0];
    const float* Wqkv = (const float*)d_in[1];
    const float* bqkv = (const float*)d_in[2];
    const float* Wo   = (const float*)d_in[3];
    const float* bo   = (const float*)d_in[4];
    float* out = (float*)d_out;

    u16* q_ws  = (u16*)d_ws;                 // 4.19M elems each
    u16* k_ws  = q_ws + 4194304;
    u16* vt_ws = k_ws + 4194304;
    u16* y_ws  = vt_ws + 4194304;
    u16* xb    = y_ws + 4194304;             // bf16 copies of inputs
    u16* wqkvb = xb + 4194304;
    u16* wob   = wqkvb + 786432;
    const size_t need = (size_t)(4194304 * 5 + 786432 + 262144) * 2;

    if (ws_size >= need) {
        cvt_k<<<4096, 256, 0, stream>>>(x, xb, 1048576);
        cvt_k<<<768, 256, 0, stream>>>(Wqkv, wqkvb, 196608);
        cvt_k<<<256, 256, 0, stream>>>(Wo, wob, 65536);
        gemm_qkv_bf<<<dim3(64, 12), 256, 0, stream>>>(xb, wqkvb, bqkv, q_ws, k_ws, vt_ws);
        attn_k<<<dim3(64, 16), 256, 0, stream>>>(q_ws, k_ws, vt_ws, y_ws);
        gemm_o_k<u16><<<dim3(64, 4), 256, 0, stream>>>(y_ws, wob, bo, out);
    } else {
        gemm_qkv_f32<<<dim3(64, 12), 256, 0, stream>>>(x, Wqkv, bqkv, q_ws, k_ws, vt_ws);
        attn_k<<<dim3(64, 16), 256, 0, stream>>>(q_ws, k_ws, vt_ws, y_ws);
        gemm_o_k<float><<<dim3(64, 4), 256, 0, stream>>>(y_ws, Wo, bo, out);
    }
}